// Round 3
// baseline (3707.133 us; speedup 1.0000x reference)
//
#include <hip/hip_runtime.h>
#include <hip/hip_bf16.h>

// Problem constants
#define NTOK 4096      // B*T
#define DDIM 1024
#define GG 4
#define EE 4
#define FF 4096
#define NEXP 16        // G*E
#define GL_OFF 4194304           // group_logits offset in d_out (floats)
#define ENT_OFF 4210688          // entropy offset

typedef float f32x4 __attribute__((ext_vector_type(4)));
typedef short short8 __attribute__((ext_vector_type(8)));

__device__ inline unsigned short f2bf(float f) {
  unsigned int u = __float_as_uint(f);
  unsigned int rounding = 0x7FFFu + ((u >> 16) & 1u);
  return (unsigned short)((u + rounding) >> 16);
}
__device__ inline unsigned int pack2(float f0, float f1) {
  return (unsigned int)f2bf(f0) | ((unsigned int)f2bf(f1) << 16);
}

// ---------------- x -> bf16 conversion ----------------
__global__ void cvt_kernel(const float* __restrict__ x, unsigned short* __restrict__ xb) {
  int idx = blockIdx.x * 256 + threadIdx.x;   // one uint4 (8 bf16) per thread
  const float4* p = reinterpret_cast<const float4*>(x) + (size_t)idx * 2;
  float4 a = p[0], b = p[1];
  uint4 v;
  v.x = pack2(a.x, a.y); v.y = pack2(a.z, a.w);
  v.z = pack2(b.x, b.y); v.w = pack2(b.z, b.w);
  reinterpret_cast<uint4*>(xb)[idx] = v;
}

// ---------------- routing ----------------
__global__ __launch_bounds__(256) void routing_kernel(
    const float* __restrict__ x, const float* __restrict__ Wg,
    const float* __restrict__ We, float* __restrict__ out,
    int* __restrict__ cnt, int* __restrict__ tokL, int* __restrict__ hrwL,
    float* __restrict__ wslot) {
  int wave = threadIdx.x >> 6, lane = threadIdx.x & 63;
  int token = blockIdx.x * 4 + wave;
  const float4* xr = reinterpret_cast<const float4*>(x + (size_t)token * DDIM);
  float4 xv[4];
#pragma unroll
  for (int c = 0; c < 4; c++) xv[c] = xr[c * 64 + lane];

  auto dotrow = [&](const float* w) -> float {
    const float4* w4 = reinterpret_cast<const float4*>(w);
    float s = 0.f;
#pragma unroll
    for (int c = 0; c < 4; c++) {
      float4 wv = w4[c * 64 + lane];
      s += xv[c].x * wv.x + xv[c].y * wv.y + xv[c].z * wv.z + xv[c].w * wv.w;
    }
#pragma unroll
    for (int off = 32; off; off >>= 1) s += __shfl_xor(s, off, 64);
    return s;
  };

  float gl[GG];
#pragma unroll
  for (int g = 0; g < GG; g++) gl[g] = dotrow(Wg + g * DDIM);

  // top-2 groups (ties -> lower index, strict >)
  int g0 = 0;
  for (int g = 1; g < GG; g++) if (gl[g] > gl[g0]) g0 = g;
  int g1 = -1;
  for (int g = 0; g < GG; g++) { if (g == g0) continue; if (g1 < 0 || gl[g] > gl[g1]) g1 = g; }
  float e1 = __expf(gl[g1] - gl[g0]);
  float inv = 1.f / (1.f + e1);
  float w0 = inv, w1 = e1 * inv;

  int gsel[2] = {g0, g1};
  float wsel[2] = {w0, w1};
  int esel[2];
#pragma unroll
  for (int r = 0; r < 2; r++) {
    float el[EE];
#pragma unroll
    for (int e = 0; e < EE; e++) el[e] = dotrow(We + ((size_t)gsel[r] * EE + e) * DDIM);
    int best = 0;
    for (int e = 1; e < EE; e++) if (el[e] > el[best]) best = e;
    esel[r] = best;
  }

  float m = gl[0];
  for (int g = 1; g < GG; g++) m = fmaxf(m, gl[g]);
  float se = 0.f;
  for (int g = 0; g < GG; g++) se += __expf(gl[g] - m);
  float lse = __logf(se);
  float ent = 0.f;
  for (int g = 0; g < GG; g++) {
    float lp = gl[g] - m - lse;
    ent -= __expf(lp) * lp;
  }

  if (lane == 0) {
    for (int g = 0; g < GG; g++) out[GL_OFF + token * GG + g] = gl[g];
    atomicAdd(out + ENT_OFF, ent * (1.0f / NTOK));
    for (int r = 0; r < 2; r++) {
      int ge = gsel[r] * EE + esel[r];
      int pos = atomicAdd(cnt + ge, 1);
      tokL[ge * NTOK + pos] = token;
      hrwL[ge * NTOK + pos] = r * NTOK + token;
      wslot[r * NTOK + token] = wsel[r];
    }
  }
}

// ---------------- 128x128 MFMA GEMM, fragment-major LDS ----------------
// C[m][n] = sum_k A[rows[m]][k] * W[ge*NDIM + n][k]   (A bf16, W fp32)
// LDS layout: 8 sub-blocks of 16 rows x 32 k; chunk c (16B) within a
// sub-block holds (row = c&15, kgroup = c>>4). Chunk index == lane index for
// both staging writes and MFMA fragment reads -> linear, conflict-free
// (0 LDS bank conflicts measured in R2). Staging uses NORMAL vector loads
// (gathered global_load_lds serialized catastrophically in R2).
template<int NDIM, int KDIM, bool GELU>
__global__ __launch_bounds__(256) void moe_gemm(
    const unsigned short* __restrict__ A,   // [*, KDIM] bf16
    const float* __restrict__ W,            // [NEXP*NDIM, KDIM] fp32
    const int* __restrict__ cnt,
    const int* __restrict__ rows,           // staging row ids [NEXP*NTOK]
    const int* __restrict__ dest,           // output slot ids [NEXP*NTOK]
    unsigned short* __restrict__ outB,      // bf16 out (GELU path), stride NDIM
    float* __restrict__ outF) {             // fp32 out, stride NDIM
  int ge = blockIdx.z;
  int count = cnt[ge];
  int mt = blockIdx.x;
  if (mt * 128 >= count) return;
  int n0 = blockIdx.y * 128;

  __shared__ alignas(16) short As[8 * 512];
  __shared__ alignas(16) short Bs[8 * 512];
  __shared__ int rowsS[128];
  __shared__ int destS[128];

  int t = threadIdx.x;
  if (t < 128) {
    int i = mt * 128 + t;
    bool v = i < count;
    rowsS[t] = v ? rows[ge * NTOK + i] : 0;
    destS[t] = v ? dest[ge * NTOK + i] : -1;
  }
  __syncthreads();

  int lane = t & 63, w = t >> 6;
  int i15 = lane & 15, ikg = lane >> 4;
  int s0 = 2 * w, s1 = s0 + 1;

  const unsigned short* ap0 = A + (size_t)rowsS[s0 * 16 + i15] * KDIM + ikg * 8;
  const unsigned short* ap1 = A + (size_t)rowsS[s1 * 16 + i15] * KDIM + ikg * 8;
  const float* bp0 = W + ((size_t)ge * NDIM + n0 + s0 * 16 + i15) * KDIM + ikg * 8;
  const float* bp1 = W + ((size_t)ge * NDIM + n0 + s1 * 16 + i15) * KDIM + ikg * 8;
  uint4* aw0 = reinterpret_cast<uint4*>(&As[s0 * 512 + lane * 8]);
  uint4* aw1 = reinterpret_cast<uint4*>(&As[s1 * 512 + lane * 8]);
  uint4* bw0 = reinterpret_cast<uint4*>(&Bs[s0 * 512 + lane * 8]);
  uint4* bw1 = reinterpret_cast<uint4*>(&Bs[s1 * 512 + lane * 8]);

  int wrow = w >> 1, wcol = w & 1;

  f32x4 acc[4][4] = {};

  // register prefetch for kb=0
  uint4 a0v = *reinterpret_cast<const uint4*>(ap0);
  uint4 a1v = *reinterpret_cast<const uint4*>(ap1);
  float4 u0 = *reinterpret_cast<const float4*>(bp0);
  float4 u1 = *reinterpret_cast<const float4*>(bp0 + 4);
  float4 v0 = *reinterpret_cast<const float4*>(bp1);
  float4 v1 = *reinterpret_cast<const float4*>(bp1 + 4);

  for (int kb = 0; kb < KDIM; kb += 32) {
    // stage prefetched A and B (fp32->bf16 pack) into LDS
    *aw0 = a0v;
    *aw1 = a1v;
    uint4 b0, b1;
    b0.x = pack2(u0.x, u0.y); b0.y = pack2(u0.z, u0.w);
    b0.z = pack2(u1.x, u1.y); b0.w = pack2(u1.z, u1.w);
    b1.x = pack2(v0.x, v0.y); b1.y = pack2(v0.z, v0.w);
    b1.z = pack2(v1.x, v1.y); b1.w = pack2(v1.z, v1.w);
    *bw0 = b0;
    *bw1 = b1;
    __syncthreads();
    // prefetch next chunk; latency hidden under the 16 MFMAs below
    if (kb + 32 < KDIM) {
      a0v = *reinterpret_cast<const uint4*>(ap0 + kb + 32);
      a1v = *reinterpret_cast<const uint4*>(ap1 + kb + 32);
      u0 = *reinterpret_cast<const float4*>(bp0 + kb + 32);
      u1 = *reinterpret_cast<const float4*>(bp0 + kb + 36);
      v0 = *reinterpret_cast<const float4*>(bp1 + kb + 32);
      v1 = *reinterpret_cast<const float4*>(bp1 + kb + 36);
    }
    short8 af[4], bf[4];
#pragma unroll
    for (int i = 0; i < 4; i++)
      af[i] = *reinterpret_cast<const short8*>(&As[(wrow * 4 + i) * 512 + lane * 8]);
#pragma unroll
    for (int j = 0; j < 4; j++)
      bf[j] = *reinterpret_cast<const short8*>(&Bs[(wcol * 4 + j) * 512 + lane * 8]);
#pragma unroll
    for (int i = 0; i < 4; i++)
#pragma unroll
      for (int j = 0; j < 4; j++)
        acc[i][j] = __builtin_amdgcn_mfma_f32_16x16x32_bf16(af[i], bf[j], acc[i][j], 0, 0, 0);
    __syncthreads();
  }

  // epilogue: C/D layout col=lane&15, row=(lane>>4)*4+reg
  int rl = ikg * 4;
#pragma unroll
  for (int i = 0; i < 4; i++) {
#pragma unroll
    for (int r = 0; r < 4; r++) {
      int ml = wrow * 64 + i * 16 + rl + r;
      int slot = destS[ml];
      if (slot < 0) continue;
      size_t base = (size_t)slot * NDIM + n0 + wcol * 64 + i15;
#pragma unroll
      for (int j = 0; j < 4; j++) {
        float vv = acc[i][j][r];
        if (GELU) {
          float gel = 0.5f * vv * (1.0f + erff(vv * 0.70710678118654752f));
          outB[base + j * 16] = f2bf(gel);
        } else {
          outF[base + j * 16] = vv;
        }
      }
    }
  }
}

// ---------------- combine: out = w0*Y0 + w1*Y1 ----------------
__global__ void combine_kernel(const float* __restrict__ Y,
                               const float* __restrict__ wslot,
                               float* __restrict__ out) {
  int idx = blockIdx.x * 256 + threadIdx.x;    // one float4 per thread
  int token = idx >> 8;                        // 256 float4 per row
  float w0 = wslot[token], w1 = wslot[NTOK + token];
  float4 a = reinterpret_cast<const float4*>(Y)[idx];
  float4 b = reinterpret_cast<const float4*>(Y + (size_t)NTOK * DDIM)[idx];
  float4 o;
  o.x = w0 * a.x + w1 * b.x;
  o.y = w0 * a.y + w1 * b.y;
  o.z = w0 * a.z + w1 * b.z;
  o.w = w0 * a.w + w1 * b.w;
  reinterpret_cast<float4*>(out)[idx] = o;
}

extern "C" void kernel_launch(void* const* d_in, const int* in_sizes, int n_in,
                              void* d_out, int out_size, void* d_ws, size_t ws_size,
                              hipStream_t stream) {
  const float* x  = (const float*)d_in[0];
  const float* Wg = (const float*)d_in[1];
  const float* We = (const float*)d_in[2];
  const float* W1 = (const float*)d_in[3];
  const float* W2 = (const float*)d_in[4];
  float* out = (float*)d_out;
  char* ws = (char*)d_ws;

  // workspace layout
  int* cnt = (int*)(ws);                               // 64 B (zeroed)
  int* tokL = (int*)(ws + 1024);                       // 16*4096*4
  int* hrwL = (int*)(ws + 1024 + 262144);              // 16*4096*4
  float* wslot = (float*)(ws + 1024 + 524288);         // 2*4096*4
  unsigned short* xb = (unsigned short*)(ws + (1 << 20));            // 8 MB
  unsigned short* H  = (unsigned short*)(ws + (1 << 20) + 8388608);  // 67 MB
  float* Y = (float*)(ws + (1 << 20) + 8388608 + 67108864);          // 33.5 MB

  hipMemsetAsync(d_out, 0, (size_t)out_size * sizeof(float), stream);
  hipMemsetAsync(ws, 0, 1024, stream);

  cvt_kernel<<<2048, 256, 0, stream>>>(x, xb);
  routing_kernel<<<1024, 256, 0, stream>>>(x, Wg, We, out, cnt, tokL, hrwL, wslot);
  // up: H = gelu(Xg @ W1^T)   M=count, N=FF, K=DDIM
  moe_gemm<FF, DDIM, true><<<dim3(32, FF / 128, NEXP), 256, 0, stream>>>(
      xb, W1, cnt, tokL, hrwL, H, nullptr);
  // down: Y = Hg @ W2^T       M=count, N=DDIM, K=FF
  moe_gemm<DDIM, FF, false><<<dim3(32, DDIM / 128, NEXP), 256, 0, stream>>>(
      H, W2, cnt, hrwL, hrwL, nullptr, Y);
  combine_kernel<<<4096, 256, 0, stream>>>(Y, wslot, out);
}

// Round 4
// 1108.713 us; speedup vs baseline: 3.3436x; 3.3436x over previous
//
#include <hip/hip_runtime.h>
#include <hip/hip_bf16.h>

// Problem constants
#define NTOK 4096      // B*T
#define DDIM 1024
#define GG 4
#define EE 4
#define FF 4096
#define NEXP 16        // G*E
#define GL_OFF 4194304           // group_logits offset in d_out (floats)
#define ENT_OFF 4210688          // entropy offset
#define MAXWL 80                 // max worklist items: sum ceil(cnt/128) <= 8192/128+16

typedef float f32x4 __attribute__((ext_vector_type(4)));
typedef short short8 __attribute__((ext_vector_type(8)));

__device__ inline unsigned short f2bf(float f) {
  unsigned int u = __float_as_uint(f);
  unsigned int rounding = 0x7FFFu + ((u >> 16) & 1u);
  return (unsigned short)((u + rounding) >> 16);
}
__device__ inline unsigned int pack2(float f0, float f1) {
  return (unsigned int)f2bf(f0) | ((unsigned int)f2bf(f1) << 16);
}

// ---------------- x -> bf16 conversion ----------------
__global__ void cvt_kernel(const float* __restrict__ x, unsigned short* __restrict__ xb) {
  int idx = blockIdx.x * 256 + threadIdx.x;   // one uint4 (8 bf16) per thread
  const float4* p = reinterpret_cast<const float4*>(x) + (size_t)idx * 2;
  float4 a = p[0], b = p[1];
  uint4 v;
  v.x = pack2(a.x, a.y); v.y = pack2(a.z, a.w);
  v.z = pack2(b.x, b.y); v.w = pack2(b.z, b.w);
  reinterpret_cast<uint4*>(xb)[idx] = v;
}

// ---------------- routing ----------------
__global__ __launch_bounds__(256) void routing_kernel(
    const float* __restrict__ x, const float* __restrict__ Wg,
    const float* __restrict__ We, float* __restrict__ out,
    int* __restrict__ cnt, int* __restrict__ tokL, int* __restrict__ hrwL,
    float* __restrict__ wslot) {
  int wave = threadIdx.x >> 6, lane = threadIdx.x & 63;
  int token = blockIdx.x * 4 + wave;
  const float4* xr = reinterpret_cast<const float4*>(x + (size_t)token * DDIM);
  float4 xv[4];
#pragma unroll
  for (int c = 0; c < 4; c++) xv[c] = xr[c * 64 + lane];

  auto dotrow = [&](const float* w) -> float {
    const float4* w4 = reinterpret_cast<const float4*>(w);
    float s = 0.f;
#pragma unroll
    for (int c = 0; c < 4; c++) {
      float4 wv = w4[c * 64 + lane];
      s += xv[c].x * wv.x + xv[c].y * wv.y + xv[c].z * wv.z + xv[c].w * wv.w;
    }
#pragma unroll
    for (int off = 32; off; off >>= 1) s += __shfl_xor(s, off, 64);
    return s;
  };

  float gl[GG];
#pragma unroll
  for (int g = 0; g < GG; g++) gl[g] = dotrow(Wg + g * DDIM);

  // top-2 groups (ties -> lower index, strict >)
  int g0 = 0;
  for (int g = 1; g < GG; g++) if (gl[g] > gl[g0]) g0 = g;
  int g1 = -1;
  for (int g = 0; g < GG; g++) { if (g == g0) continue; if (g1 < 0 || gl[g] > gl[g1]) g1 = g; }
  float e1 = __expf(gl[g1] - gl[g0]);
  float inv = 1.f / (1.f + e1);
  float w0 = inv, w1 = e1 * inv;

  int gsel[2] = {g0, g1};
  float wsel[2] = {w0, w1};
  int esel[2];
#pragma unroll
  for (int r = 0; r < 2; r++) {
    float el[EE];
#pragma unroll
    for (int e = 0; e < EE; e++) el[e] = dotrow(We + ((size_t)gsel[r] * EE + e) * DDIM);
    int best = 0;
    for (int e = 1; e < EE; e++) if (el[e] > el[best]) best = e;
    esel[r] = best;
  }

  float m = gl[0];
  for (int g = 1; g < GG; g++) m = fmaxf(m, gl[g]);
  float se = 0.f;
  for (int g = 0; g < GG; g++) se += __expf(gl[g] - m);
  float lse = __logf(se);
  float ent = 0.f;
  for (int g = 0; g < GG; g++) {
    float lp = gl[g] - m - lse;
    ent -= __expf(lp) * lp;
  }

  if (lane == 0) {
    for (int g = 0; g < GG; g++) out[GL_OFF + token * GG + g] = gl[g];
    atomicAdd(out + ENT_OFF, ent * (1.0f / NTOK));
    for (int r = 0; r < 2; r++) {
      int ge = gsel[r] * EE + esel[r];
      int pos = atomicAdd(cnt + ge, 1);
      tokL[ge * NTOK + pos] = token;
      hrwL[ge * NTOK + pos] = r * NTOK + token;
      wslot[r * NTOK + token] = wsel[r];
    }
  }
}

// ---------------- worklist build: compacted (ge, mt) items ----------------
// Kills the dispatch-order aliasing: active GEMM blocks become a contiguous
// prefix of the grid instead of a mod-32 periodic subset (which aliased onto
// 1/8 of the XCD/CU stripes in R2/R3 -> 3% occupancy).
__global__ void wl_kernel(const int* __restrict__ cnt, int* __restrict__ wl,
                          int* __restrict__ wlN) {
  if (threadIdx.x == 0) {
    int p = 0;
    for (int ge = 0; ge < NEXP; ge++) {
      int tiles = (cnt[ge] + 127) >> 7;
      for (int mt = 0; mt < tiles; mt++) wl[p++] = (ge << 16) | mt;
    }
    wlN[0] = p;
  }
}

// ---------------- 128x128 MFMA GEMM, fragment-major LDS ----------------
// C[m][n] = sum_k A[rows[m]][k] * W[ge*NDIM + n][k]   (A bf16, W fp32)
// LDS layout: 8 sub-blocks of 16 rows x 32 k; chunk c (16B) within a
// sub-block holds (row = c&15, kgroup = c>>4). Chunk index == lane index for
// staging writes and MFMA fragment reads -> conflict-free (0 measured).
// blockIdx.x = n-tile (all active, fastest-varying); blockIdx.y = worklist
// item; duds are a contiguous tail.
template<int NDIM, int KDIM, bool GELU>
__global__ __launch_bounds__(256) void moe_gemm(
    const unsigned short* __restrict__ A,   // [*, KDIM] bf16
    const float* __restrict__ W,            // [NEXP*NDIM, KDIM] fp32
    const int* __restrict__ cnt,
    const int* __restrict__ wl, const int* __restrict__ wlN,
    const int* __restrict__ rows,           // staging row ids [NEXP*NTOK]
    const int* __restrict__ dest,           // output slot ids [NEXP*NTOK]
    unsigned short* __restrict__ outB,      // bf16 out (GELU path), stride NDIM
    float* __restrict__ outF) {             // fp32 out, stride NDIM
  int item = blockIdx.y;
  if (item >= wlN[0]) return;
  int packed = wl[item];
  int ge = packed >> 16, mt = packed & 0xffff;
  int count = cnt[ge];
  int n0 = blockIdx.x * 128;

  __shared__ alignas(16) short As[8 * 512];
  __shared__ alignas(16) short Bs[8 * 512];
  __shared__ int rowsS[128];
  __shared__ int destS[128];

  int t = threadIdx.x;
  if (t < 128) {
    int i = mt * 128 + t;
    bool v = i < count;
    rowsS[t] = v ? rows[ge * NTOK + i] : 0;
    destS[t] = v ? dest[ge * NTOK + i] : -1;
  }
  __syncthreads();

  int lane = t & 63, w = t >> 6;
  int i15 = lane & 15, ikg = lane >> 4;
  int s0 = 2 * w, s1 = s0 + 1;

  const unsigned short* ap0 = A + (size_t)rowsS[s0 * 16 + i15] * KDIM + ikg * 8;
  const unsigned short* ap1 = A + (size_t)rowsS[s1 * 16 + i15] * KDIM + ikg * 8;
  const float* bp0 = W + ((size_t)ge * NDIM + n0 + s0 * 16 + i15) * KDIM + ikg * 8;
  const float* bp1 = W + ((size_t)ge * NDIM + n0 + s1 * 16 + i15) * KDIM + ikg * 8;
  uint4* aw0 = reinterpret_cast<uint4*>(&As[s0 * 512 + lane * 8]);
  uint4* aw1 = reinterpret_cast<uint4*>(&As[s1 * 512 + lane * 8]);
  uint4* bw0 = reinterpret_cast<uint4*>(&Bs[s0 * 512 + lane * 8]);
  uint4* bw1 = reinterpret_cast<uint4*>(&Bs[s1 * 512 + lane * 8]);

  int wrow = w >> 1, wcol = w & 1;

  f32x4 acc[4][4] = {};

  // register prefetch for kb=0
  uint4 a0v = *reinterpret_cast<const uint4*>(ap0);
  uint4 a1v = *reinterpret_cast<const uint4*>(ap1);
  float4 u0 = *reinterpret_cast<const float4*>(bp0);
  float4 u1 = *reinterpret_cast<const float4*>(bp0 + 4);
  float4 v0 = *reinterpret_cast<const float4*>(bp1);
  float4 v1 = *reinterpret_cast<const float4*>(bp1 + 4);

  for (int kb = 0; kb < KDIM; kb += 32) {
    // stage prefetched A and B (fp32->bf16 pack) into LDS
    *aw0 = a0v;
    *aw1 = a1v;
    uint4 b0, b1;
    b0.x = pack2(u0.x, u0.y); b0.y = pack2(u0.z, u0.w);
    b0.z = pack2(u1.x, u1.y); b0.w = pack2(u1.z, u1.w);
    b1.x = pack2(v0.x, v0.y); b1.y = pack2(v0.z, v0.w);
    b1.z = pack2(v1.x, v1.y); b1.w = pack2(v1.z, v1.w);
    *bw0 = b0;
    *bw1 = b1;
    __syncthreads();
    // prefetch next chunk; latency hidden under the 16 MFMAs below
    if (kb + 32 < KDIM) {
      a0v = *reinterpret_cast<const uint4*>(ap0 + kb + 32);
      a1v = *reinterpret_cast<const uint4*>(ap1 + kb + 32);
      u0 = *reinterpret_cast<const float4*>(bp0 + kb + 32);
      u1 = *reinterpret_cast<const float4*>(bp0 + kb + 36);
      v0 = *reinterpret_cast<const float4*>(bp1 + kb + 32);
      v1 = *reinterpret_cast<const float4*>(bp1 + kb + 36);
    }
    short8 af[4], bf[4];
#pragma unroll
    for (int i = 0; i < 4; i++)
      af[i] = *reinterpret_cast<const short8*>(&As[(wrow * 4 + i) * 512 + lane * 8]);
#pragma unroll
    for (int j = 0; j < 4; j++)
      bf[j] = *reinterpret_cast<const short8*>(&Bs[(wcol * 4 + j) * 512 + lane * 8]);
#pragma unroll
    for (int i = 0; i < 4; i++)
#pragma unroll
      for (int j = 0; j < 4; j++)
        acc[i][j] = __builtin_amdgcn_mfma_f32_16x16x32_bf16(af[i], bf[j], acc[i][j], 0, 0, 0);
    __syncthreads();
  }

  // epilogue: C/D layout col=lane&15, row=(lane>>4)*4+reg
  int rl = ikg * 4;
#pragma unroll
  for (int i = 0; i < 4; i++) {
#pragma unroll
    for (int r = 0; r < 4; r++) {
      int ml = wrow * 64 + i * 16 + rl + r;
      int slot = destS[ml];
      if (slot < 0) continue;
      size_t base = (size_t)slot * NDIM + n0 + wcol * 64 + i15;
#pragma unroll
      for (int j = 0; j < 4; j++) {
        float vv = acc[i][j][r];
        if (GELU) {
          float gel = 0.5f * vv * (1.0f + erff(vv * 0.70710678118654752f));
          outB[base + j * 16] = f2bf(gel);
        } else {
          outF[base + j * 16] = vv;
        }
      }
    }
  }
}

// ---------------- combine: out = w0*Y0 + w1*Y1 ----------------
__global__ void combine_kernel(const float* __restrict__ Y,
                               const float* __restrict__ wslot,
                               float* __restrict__ out) {
  int idx = blockIdx.x * 256 + threadIdx.x;    // one float4 per thread
  int token = idx >> 8;                        // 256 float4 per row
  float w0 = wslot[token], w1 = wslot[NTOK + token];
  float4 a = reinterpret_cast<const float4*>(Y)[idx];
  float4 b = reinterpret_cast<const float4*>(Y + (size_t)NTOK * DDIM)[idx];
  float4 o;
  o.x = w0 * a.x + w1 * b.x;
  o.y = w0 * a.y + w1 * b.y;
  o.z = w0 * a.z + w1 * b.z;
  o.w = w0 * a.w + w1 * b.w;
  reinterpret_cast<float4*>(out)[idx] = o;
}

extern "C" void kernel_launch(void* const* d_in, const int* in_sizes, int n_in,
                              void* d_out, int out_size, void* d_ws, size_t ws_size,
                              hipStream_t stream) {
  const float* x  = (const float*)d_in[0];
  const float* Wg = (const float*)d_in[1];
  const float* We = (const float*)d_in[2];
  const float* W1 = (const float*)d_in[3];
  const float* W2 = (const float*)d_in[4];
  float* out = (float*)d_out;
  char* ws = (char*)d_ws;

  // workspace layout
  int* cnt = (int*)(ws);                               // 64 B (zeroed)
  int* tokL = (int*)(ws + 1024);                       // 16*4096*4
  int* hrwL = (int*)(ws + 1024 + 262144);              // 16*4096*4
  float* wslot = (float*)(ws + 1024 + 524288);         // 2*4096*4
  int* wl  = (int*)(ws + 786432);                      // MAXWL ints
  int* wlN = (int*)(ws + 786432 + 512);                // 1 int
  unsigned short* xb = (unsigned short*)(ws + (1 << 20));            // 8 MB
  unsigned short* H  = (unsigned short*)(ws + (1 << 20) + 8388608);  // 67 MB
  float* Y = (float*)(ws + (1 << 20) + 8388608 + 67108864);          // 33.5 MB

  hipMemsetAsync(d_out, 0, (size_t)out_size * sizeof(float), stream);
  hipMemsetAsync(ws, 0, 1024, stream);

  cvt_kernel<<<2048, 256, 0, stream>>>(x, xb);
  routing_kernel<<<1024, 256, 0, stream>>>(x, Wg, We, out, cnt, tokL, hrwL, wslot);
  wl_kernel<<<1, 64, 0, stream>>>(cnt, wl, wlN);
  // up: H = gelu(Xg @ W1^T)   M=count, N=FF, K=DDIM
  moe_gemm<FF, DDIM, true><<<dim3(FF / 128, MAXWL), 256, 0, stream>>>(
      xb, W1, cnt, wl, wlN, tokL, hrwL, H, nullptr);
  // down: Y = Hg @ W2^T       M=count, N=DDIM, K=FF
  moe_gemm<DDIM, FF, false><<<dim3(DDIM / 128, MAXWL), 256, 0, stream>>>(
      H, W2, cnt, wl, wlN, hrwL, hrwL, nullptr, Y);
  combine_kernel<<<4096, 256, 0, stream>>>(Y, wslot, out);
}